// Round 17
// baseline (164.415 us; speedup 1.0000x reference)
//
#include <hip/hip_runtime.h>
#include <stdint.h>

typedef _Float16 half8 __attribute__((ext_vector_type(8)));
typedef _Float16 half4v __attribute__((ext_vector_type(4)));
typedef float floatx4 __attribute__((ext_vector_type(4)));
typedef float floatx16 __attribute__((ext_vector_type(16)));
typedef long long i64v;

#define TT 4096
#define DH 512

#define WAITLGKM() asm volatile("s_waitcnt lgkmcnt(0)" ::: "memory")
#define BAR() __builtin_amdgcn_s_barrier()
#define FENCE() asm volatile("" ::: "memory")

__device__ __forceinline__ unsigned short f2h(float f) {
    union { _Float16 h; unsigned short u; } v;
    v.h = (_Float16)f;
    return v.u;
}

// ---------- kernel 1: normalize right half of x -> xn (fp16) + xn8 (e4m3, x16 scale) ----------
__global__ void norm_k(const float* __restrict__ x, unsigned short* __restrict__ xn,
                       unsigned char* __restrict__ xn8) {
    const int w = threadIdx.x >> 6, l = threadIdx.x & 63;
    const int row = blockIdx.x * 4 + w;              // 0 .. B*T-1
    const float* src = x + (size_t)row * 1024 + 512 + l * 8;
    floatx4 a = *(const floatx4*)src;
    floatx4 c = *(const floatx4*)(src + 4);
    float s = a[0]*a[0] + a[1]*a[1] + a[2]*a[2] + a[3]*a[3]
            + c[0]*c[0] + c[1]*c[1] + c[2]*c[2] + c[3]*c[3];
    #pragma unroll
    for (int off = 32; off > 0; off >>= 1) s += __shfl_xor(s, off);
    const float scale = 1.0f / fmaxf(sqrtf(s), 1e-12f);
    float v[8] = {a[0], a[1], a[2], a[3], c[0], c[1], c[2], c[3]};
    uint32_t pk[4];
    #pragma unroll
    for (int i = 0; i < 4; i++)
        pk[i] = (uint32_t)f2h(v[2*i] * scale) | ((uint32_t)f2h(v[2*i+1] * scale) << 16);
    uint4 o; o.x = pk[0]; o.y = pk[1]; o.z = pk[2]; o.w = pk[3];
    *(uint4*)(xn + (size_t)row * DH + l * 8) = o;
    // fp8 e4m3 copy, scaled x16
    const float s16 = scale * 16.0f;
    int pa = __builtin_amdgcn_cvt_pk_fp8_f32(v[0]*s16, v[1]*s16, 0, 0);
    pa     = __builtin_amdgcn_cvt_pk_fp8_f32(v[2]*s16, v[3]*s16, pa, 1);
    int pb = __builtin_amdgcn_cvt_pk_fp8_f32(v[4]*s16, v[5]*s16, 0, 0);
    pb     = __builtin_amdgcn_cvt_pk_fp8_f32(v[6]*s16, v[7]*s16, pb, 1);
    uint2 o8; o8.x = (uint32_t)pa; o8.y = (uint32_t)pb;
    *(uint2*)(xn8 + (size_t)row * DH + l * 8) = o8;
}

// ---------- kernel 2: xnT8[b][d][t] = fp8(xn[b][t][d] * 16), 64x64 LDS tile transpose ----------
__global__ void transpose_k(const unsigned short* __restrict__ xn,
                            unsigned char* __restrict__ xnT8) {
    __shared__ __align__(16) unsigned short tile[64 * 72];  // +8 pad
    const int b = blockIdx.z;
    const int t0 = blockIdx.x * 64, d0 = blockIdx.y * 64;
    const int tid = threadIdx.x;
    #pragma unroll
    for (int i = 0; i < 2; i++) {
        int c = i * 256 + tid;
        int tr = c >> 3, d8 = c & 7;
        uint4 vv = *(const uint4*)(xn + ((size_t)(b * TT + t0 + tr) * DH + d0 + d8 * 8));
        *(uint4*)&tile[tr * 72 + d8 * 8] = vv;
    }
    __syncthreads();
    #pragma unroll
    for (int i = 0; i < 2; i++) {
        int c = i * 256 + tid;
        int dd = c >> 3, t8 = c & 7;
        float f[8];
        #pragma unroll
        for (int k = 0; k < 8; k++) {
            unsigned short u = tile[(t8 * 8 + k) * 72 + dd];
            f[k] = (float)(*(const _Float16*)&u) * 16.0f;
        }
        int pa = __builtin_amdgcn_cvt_pk_fp8_f32(f[0], f[1], 0, 0);
        pa     = __builtin_amdgcn_cvt_pk_fp8_f32(f[2], f[3], pa, 1);
        int pb = __builtin_amdgcn_cvt_pk_fp8_f32(f[4], f[5], 0, 0);
        pb     = __builtin_amdgcn_cvt_pk_fp8_f32(f[6], f[7], pb, 1);
        uint2 o8; o8.x = (uint32_t)pa; o8.y = (uint32_t)pb;
        *(uint2*)(xnT8 + ((size_t)(b * DH + d0 + dd) * TT + t0 + t8 * 8)) = o8;
    }
}

// ---------- kernel 3: R16 + double-buffered Sred -> 2 barriers/tile ----------
// Wave w: step1 role (g=w>>2, mi=(w>>1)&1, dh=w&1): S^T partial p=g*2+dh over K=128, fp8;
//   step3/epilogue role: d-slice [w*64, w*64+64), fp8 (W8 = S256*V; acc x4096).
// Sred double-buffered [2][4][64][64] fp16: tile t uses buffer t&1 -> the next tile's
// Sred writes never touch what reduce[t]/step3[t] read, so BAR_D is removed.
// Cross-tile WAR (Sred[t&1] rewritten at t+2) is fenced by BAR_B[t+1]+BAR_C[t+1].
// Per tile (2 barriers):
//   vmcnt(6) [kn8 landed; kt8 4 + V 2 in flight]
//   step1 (8 b64 rd, 16 fp8-mfma) ; Sred[t&1] wr ; issue kn8[t+1] ; lgkm ; BAR_B
//   reduce (8 b64) ; vmcnt(4) ; W8 = fp8(S256*V) wr to OWN bytes ; lgkm ; BAR_C
//   step3 (8 b64 W8 + 8 b64 kt8, 16 fp8-mfma) ; issue kt8[t+1]+V[t+1] ; (no barrier)
// LDS 128 KiB: kn8[8w][4KB] 32K | kt8[8w][4KB] 32K | Sred[2][4][64][64]f16 64K (p0 bytes = W8).
__global__ __launch_bounds__(512, 2) void fused_k(
    const unsigned char* __restrict__ xn8, const unsigned char* __restrict__ xnT8,
    const float* __restrict__ V, const float* __restrict__ bias,
    const float* __restrict__ x, float* __restrict__ out)
{
    __shared__ __align__(16) unsigned char smemB[131072];   // 128 KiB
    unsigned char*  kn8B  = smemB;                           // 32 KiB
    unsigned char*  kt8B  = smemB + 32768;                   // 32 KiB
    unsigned short* SredL = (unsigned short*)(smemB + 65536); // 64 KiB: [2][4][64][64] fp16

    const int tid = threadIdx.x;
    const int w = tid >> 6, l = tid & 63;
    const int h = l >> 5, m32 = l & 31;
    const int g = w >> 2, mi = (w >> 1) & 1, dh = w & 1;
    const int p = g * 2 + dh;
    const int wk0 = g * 256 + dh * 128;      // step1 k-range base
    const int wd0 = w * 64;                  // step3 d-slice base

    // XCD-aware swizzle
    const int flat = blockIdx.y * 64 + blockIdx.x;
    const int work = (flat & 7) * 32 + (flat >> 3);
    const int b = work >> 6, qt = work & 63;
    const int q0 = qt * 64;

    const unsigned char* x8b = xn8  + (size_t)b * TT * DH;
    const unsigned char* xt8 = xnT8 + (size_t)b * DH * TT;

    unsigned char* knP8 = kn8B + w * 4096;
    unsigned char* ktP8 = kt8B + w * 4096;

    // reduce-phase mapping: q-row tq, kk group to
    const int tq = tid >> 3, to = tid & 7;
    const float* vptr = V + (size_t)(q0 + tq) * TT + to * 8;
    const int keyR = tq & 15;
    const int aLo = ((to * 2    ) ^ keyR) * 4;
    const int aHi = ((to * 2 + 1) ^ keyR) * 4;

    // ---- prologue: Q fp8 fragments (B-operand): lane q=q0+ni*32+m32
    i64v qf8[2][8];
    #pragma unroll
    for (int ni = 0; ni < 2; ni++)
        #pragma unroll
        for (int ks = 0; ks < 8; ks++)
            qf8[ni][ks] = *(const i64v*)(x8b + (size_t)(q0 + ni*32 + m32) * DH
                                         + wk0 + ks*16 + h*8);
    FENCE();
    // stage kn8[0]: 4 gll, 8 rows each; 16B-chunk pre-swizzle c^(row&7)
    #pragma unroll
    for (int i = 0; i < 4; i++) {
        int r = i * 8 + (l >> 3);
        int dg = (l & 7) ^ (r & 7);
        const unsigned char* gp = x8b + (size_t)(mi*32 + r) * DH + wk0 + dg * 16;
        __builtin_amdgcn_global_load_lds(
            (const __attribute__((address_space(1))) void*)gp,
            (__attribute__((address_space(3))) void*)&knP8[i * 1024], 16, 0, 0);
    }
    FENCE();
    // stage kt8[0]: 4 gll, 16 d-rows each; 16B-chunk pre-swizzle c^((row>>1)&3)
    #pragma unroll
    for (int i = 0; i < 4; i++) {
        int dr = i * 16 + (l >> 2);
        int cs = (l & 3) ^ ((dr >> 1) & 3);
        const unsigned char* gp = xt8 + (size_t)(wd0 + dr) * TT + cs * 16;
        __builtin_amdgcn_global_load_lds(
            (const __attribute__((address_space(1))) void*)gp,
            (__attribute__((address_space(3))) void*)&ktP8[i * 1024], 16, 0, 0);
    }
    FENCE();
    floatx4 vf0 = *(const floatx4*)(vptr);
    floatx4 vf1 = *(const floatx4*)(vptr + 4);

    floatx16 acc[2][2];
    #pragma unroll
    for (int i = 0; i < 2; i++)
        #pragma unroll
        for (int j = 0; j < 2; j++)
            acc[i][j] = (floatx16)(0.f);

    #pragma unroll 1
    for (int t = 0; t < 64; t++) {
        unsigned short* Sb = SredL + (t & 1) * 16384;        // this tile's Sred buffer
        // ---- kn8[t] landed (kt8[t] 4 + V[t] 2 stay in flight) ----
        asm volatile("s_waitcnt vmcnt(6)" ::: "memory");

        // ---- step1 (fp8): S^T partial p, rows mi; 8 b64 reads, 16 mfma ----
        floatx16 s0 = (floatx16)(0.f), s1 = (floatx16)(0.f);
        __builtin_amdgcn_s_setprio(1);
        #pragma unroll
        for (int ks = 0; ks < 8; ks++) {
            i64v a8 = *(const i64v*)&knP8[m32 * 128 + ((ks ^ (m32 & 7)) * 16) + h * 8];
            s0 = __builtin_amdgcn_mfma_f32_32x32x16_fp8_fp8(a8, qf8[0][ks], s0, 0, 0, 0);
            s1 = __builtin_amdgcn_mfma_f32_32x32x16_fp8_fp8(a8, qf8[1][ks], s1, 0, 0, 0);
        }
        __builtin_amdgcn_s_setprio(0);

        // ---- Sred write (fp16): [t&1][p][q][unit u ^ (q&15)], b64 ----
        #pragma unroll
        for (int ni = 0; ni < 2; ni++) {
            const int q = ni * 32 + m32;
            unsigned short* sp = Sb + p * 4096 + q * 64;
            const int key = q & 15;
            #pragma unroll
            for (int rr = 0; rr < 4; rr++) {
                int u = (mi * 8 + rr * 2 + h) ^ key;
                half4v v4;
                if (ni == 0) {
                    v4[0]=(_Float16)s0[rr*4+0]; v4[1]=(_Float16)s0[rr*4+1];
                    v4[2]=(_Float16)s0[rr*4+2]; v4[3]=(_Float16)s0[rr*4+3];
                } else {
                    v4[0]=(_Float16)s1[rr*4+0]; v4[1]=(_Float16)s1[rr*4+1];
                    v4[2]=(_Float16)s1[rr*4+2]; v4[3]=(_Float16)s1[rr*4+3];
                }
                *(half4v*)&sp[u * 4] = v4;
            }
        }
        // ---- issue kn8[t+1] ----
        if (t < 63) {
            FENCE();
            #pragma unroll
            for (int i = 0; i < 4; i++) {
                int r = i * 8 + (l >> 3);
                int dg = (l & 7) ^ (r & 7);
                const unsigned char* gp = x8b + (size_t)((t+1)*64 + mi*32 + r) * DH + wk0 + dg * 16;
                __builtin_amdgcn_global_load_lds(
                    (const __attribute__((address_space(1))) void*)gp,
                    (__attribute__((address_space(3))) void*)&knP8[i * 1024], 16, 0, 0);
            }
            FENCE();
        }
        WAITLGKM();
        BAR();   // BAR_B: Sred[t&1] complete

        // ---- reduce: 4 partials x 2 b64 (fp16), then W8 = fp8(S256 * V) ----
        half4v l0 = *(const half4v*)&Sb[        tq * 64 + aLo];
        half4v h0 = *(const half4v*)&Sb[        tq * 64 + aHi];
        half4v l1 = *(const half4v*)&Sb[4096  + tq * 64 + aLo];
        half4v h1 = *(const half4v*)&Sb[4096  + tq * 64 + aHi];
        half4v l2 = *(const half4v*)&Sb[8192  + tq * 64 + aLo];
        half4v h2 = *(const half4v*)&Sb[8192  + tq * 64 + aHi];
        half4v l3 = *(const half4v*)&Sb[12288 + tq * 64 + aLo];
        half4v h3 = *(const half4v*)&Sb[12288 + tq * 64 + aHi];
        half4v sLo = (l0 + l1) + (l2 + l3);
        half4v sHi = (h0 + h1) + (h2 + h3);
        if (t < 63) { asm volatile("s_waitcnt vmcnt(4)" ::: "memory"); }
        else        { asm volatile("s_waitcnt vmcnt(0)" ::: "memory"); }
        {
            float w0 = (float)sLo[0]*vf0[0], w1 = (float)sLo[1]*vf0[1];
            float w2 = (float)sLo[2]*vf0[2], w3 = (float)sLo[3]*vf0[3];
            float w4 = (float)sHi[0]*vf1[0], w5 = (float)sHi[1]*vf1[1];
            float w6 = (float)sHi[2]*vf1[2], w7 = (float)sHi[3]*vf1[3];
            int pa = __builtin_amdgcn_cvt_pk_fp8_f32(w0, w1, 0, 0);
            pa     = __builtin_amdgcn_cvt_pk_fp8_f32(w2, w3, pa, 1);
            int pb = __builtin_amdgcn_cvt_pk_fp8_f32(w4, w5, 0, 0);
            pb     = __builtin_amdgcn_cvt_pk_fp8_f32(w6, w7, pb, 1);
            uint2 w8w; w8w.x = (uint32_t)pa; w8w.y = (uint32_t)pb;
            // own-bytes overlay on Sred[t&1]-p0 (8B this thread just read)
            *(uint2*)((unsigned char*)Sb + tq * 128 + ((2*to) ^ keyR) * 8) = w8w;
        }
        WAITLGKM();
        BAR();   // BAR_C: W8 ready

        // ---- step3 (fp8): ctx[q][wd0..+64] += W8 * Kt8 ; acc = 4096*ctx ----
        const unsigned char* W8 = (const unsigned char*)Sb;
        const int keyA = m32 & 15;
        const int k2 = (m32 >> 1) & 3;
        __builtin_amdgcn_s_setprio(1);
        #pragma unroll
        for (int ks = 0; ks < 4; ks++) {
            const int u0 = ks * 4 + h * 2;
            i64v wf0 = *(const i64v*)&W8[(m32     ) * 128 + ((u0 ^ keyA) * 8)];
            i64v wf1 = *(const i64v*)&W8[(32 + m32) * 128 + ((u0 ^ keyA) * 8)];
            const int ko = ((ks ^ k2) * 16) + h * 8;
            i64v kf0 = *(const i64v*)&ktP8[(m32     ) * 64 + ko];
            i64v kf1 = *(const i64v*)&ktP8[(32 + m32) * 64 + ko];
            acc[0][0] = __builtin_amdgcn_mfma_f32_32x32x16_fp8_fp8(wf0, kf0, acc[0][0], 0, 0, 0);
            acc[0][1] = __builtin_amdgcn_mfma_f32_32x32x16_fp8_fp8(wf0, kf1, acc[0][1], 0, 0, 0);
            acc[1][0] = __builtin_amdgcn_mfma_f32_32x32x16_fp8_fp8(wf1, kf0, acc[1][0], 0, 0, 0);
            acc[1][1] = __builtin_amdgcn_mfma_f32_32x32x16_fp8_fp8(wf1, kf1, acc[1][1], 0, 0, 0);
        }
        __builtin_amdgcn_s_setprio(0);
        // ---- issue kt8[t+1] + V[t+1] (own-slice; own reads retired via mfma operand waits) ----
        if (t < 63) {
            WAITLGKM();
            FENCE();
            #pragma unroll
            for (int i = 0; i < 4; i++) {
                int dr = i * 16 + (l >> 2);
                int cs = (l & 3) ^ ((dr >> 1) & 3);
                const unsigned char* gp = xt8 + (size_t)(wd0 + dr) * TT + (t+1)*64 + cs * 16;
                __builtin_amdgcn_global_load_lds(
                    (const __attribute__((address_space(1))) void*)gp,
                    (__attribute__((address_space(3))) void*)&ktP8[i * 1024], 16, 0, 0);
            }
            FENCE();
            vf0 = *(const floatx4*)(vptr + (t+1)*64);
            vf1 = *(const floatx4*)(vptr + (t+1)*64 + 4);
            FENCE();
        }
        // no BAR_D: next tile's Sred writes go to the other buffer
    }

    // ---- epilogue: out = x_left * sigmoid(ctx/4096 + bias) ----
    const float* xb = x + (size_t)b * TT * 1024;
    float* ob = out + (size_t)b * TT * DH;
    const float isc = 1.0f / 4096.0f;
    #pragma unroll
    for (int mi2 = 0; mi2 < 2; mi2++)
        #pragma unroll
        for (int nd = 0; nd < 2; nd++) {
            int d = wd0 + nd * 32 + m32;
            float bv = bias[d];
            #pragma unroll
            for (int r = 0; r < 16; r++) {
                int q = q0 + mi2 * 32 + (r & 3) + 8 * (r >> 2) + 4 * h;
                float cv = acc[mi2][nd][r] * isc + bv;
                float gate = 1.0f / (1.0f + __expf(-cv));
                ob[(size_t)q * DH + d] = xb[(size_t)q * 1024 + d] * gate;
            }
        }
}

extern "C" void kernel_launch(void* const* d_in, const int* in_sizes, int n_in,
                              void* d_out, int out_size, void* d_ws, size_t ws_size,
                              hipStream_t stream) {
    const float* x    = (const float*)d_in[0];
    const float* V    = (const float*)d_in[1];
    const float* bias = (const float*)d_in[2];
    float* out = (float*)d_out;

    unsigned short* xn   = (unsigned short*)d_ws;                   // [4][4096][512] fp16, 16MB
    unsigned char*  xn8  = (unsigned char*)(xn + (size_t)4 * TT * DH);  // fp8, 8MB
    unsigned char*  xnT8 = xn8 + (size_t)4 * TT * DH;               // [4][512][4096] fp8, 8MB

    norm_k<<<dim3(4 * TT / 4), 256, 0, stream>>>(x, xn, xn8);
    transpose_k<<<dim3(TT / 64, DH / 64, 4), 256, 0, stream>>>(xn, xnT8);
    fused_k<<<dim3(TT / 64, 4), 512, 0, stream>>>(xn8, xnT8, V, bias, x, out);
}

// Round 19
// 143.745 us; speedup vs baseline: 1.1438x; 1.1438x over previous
//
#include <hip/hip_runtime.h>
#include <stdint.h>

typedef _Float16 half8 __attribute__((ext_vector_type(8)));
typedef float floatx4 __attribute__((ext_vector_type(4)));
typedef float floatx16 __attribute__((ext_vector_type(16)));
typedef long long i64v;

#define TT 4096
#define DH 512

#define WAITLGKM() asm volatile("s_waitcnt lgkmcnt(0)" ::: "memory")
#define BAR() __builtin_amdgcn_s_barrier()
#define FENCE() asm volatile("" ::: "memory")

__device__ __forceinline__ unsigned short f2h(float f) {
    union { _Float16 h; unsigned short u; } v;
    v.h = (_Float16)f;
    return v.u;
}

// ---------- kernel 1: normalize right half of x -> xn (fp16) + xn8 (e4m3, x16 scale) ----------
__global__ void norm_k(const float* __restrict__ x, unsigned short* __restrict__ xn,
                       unsigned char* __restrict__ xn8) {
    const int w = threadIdx.x >> 6, l = threadIdx.x & 63;
    const int row = blockIdx.x * 4 + w;              // 0 .. B*T-1
    const float* src = x + (size_t)row * 1024 + 512 + l * 8;
    floatx4 a = *(const floatx4*)src;
    floatx4 c = *(const floatx4*)(src + 4);
    float s = a[0]*a[0] + a[1]*a[1] + a[2]*a[2] + a[3]*a[3]
            + c[0]*c[0] + c[1]*c[1] + c[2]*c[2] + c[3]*c[3];
    #pragma unroll
    for (int off = 32; off > 0; off >>= 1) s += __shfl_xor(s, off);
    const float scale = 1.0f / fmaxf(sqrtf(s), 1e-12f);
    float v[8] = {a[0], a[1], a[2], a[3], c[0], c[1], c[2], c[3]};
    uint32_t pk[4];
    #pragma unroll
    for (int i = 0; i < 4; i++)
        pk[i] = (uint32_t)f2h(v[2*i] * scale) | ((uint32_t)f2h(v[2*i+1] * scale) << 16);
    uint4 o; o.x = pk[0]; o.y = pk[1]; o.z = pk[2]; o.w = pk[3];
    *(uint4*)(xn + (size_t)row * DH + l * 8) = o;
    const float s16 = scale * 16.0f;
    int pa = __builtin_amdgcn_cvt_pk_fp8_f32(v[0]*s16, v[1]*s16, 0, 0);
    pa     = __builtin_amdgcn_cvt_pk_fp8_f32(v[2]*s16, v[3]*s16, pa, 1);
    int pb = __builtin_amdgcn_cvt_pk_fp8_f32(v[4]*s16, v[5]*s16, 0, 0);
    pb     = __builtin_amdgcn_cvt_pk_fp8_f32(v[6]*s16, v[7]*s16, pb, 1);
    uint2 o8; o8.x = (uint32_t)pa; o8.y = (uint32_t)pb;
    *(uint2*)(xn8 + (size_t)row * DH + l * 8) = o8;
}

// ---------- kernel 2: xnT8[b][d][t] = fp8(xn[b][t][d] * 16), 64x64 LDS tile transpose ----------
__global__ void transpose_k(const unsigned short* __restrict__ xn,
                            unsigned char* __restrict__ xnT8) {
    __shared__ __align__(16) unsigned short tile[64 * 72];  // +8 pad
    const int b = blockIdx.z;
    const int t0 = blockIdx.x * 64, d0 = blockIdx.y * 64;
    const int tid = threadIdx.x;
    #pragma unroll
    for (int i = 0; i < 2; i++) {
        int c = i * 256 + tid;
        int tr = c >> 3, d8 = c & 7;
        uint4 vv = *(const uint4*)(xn + ((size_t)(b * TT + t0 + tr) * DH + d0 + d8 * 8));
        *(uint4*)&tile[tr * 72 + d8 * 8] = vv;
    }
    __syncthreads();
    #pragma unroll
    for (int i = 0; i < 2; i++) {
        int c = i * 256 + tid;
        int dd = c >> 3, t8 = c & 7;
        float f[8];
        #pragma unroll
        for (int k = 0; k < 8; k++) {
            unsigned short u = tile[(t8 * 8 + k) * 72 + dd];
            f[k] = (float)(*(const _Float16*)&u) * 16.0f;
        }
        int pa = __builtin_amdgcn_cvt_pk_fp8_f32(f[0], f[1], 0, 0);
        pa     = __builtin_amdgcn_cvt_pk_fp8_f32(f[2], f[3], pa, 1);
        int pb = __builtin_amdgcn_cvt_pk_fp8_f32(f[4], f[5], 0, 0);
        pb     = __builtin_amdgcn_cvt_pk_fp8_f32(f[6], f[7], pb, 1);
        uint2 o8; o8.x = (uint32_t)pa; o8.y = (uint32_t)pb;
        *(uint2*)(xnT8 + ((size_t)(b * DH + d0 + dd) * TT + t0 + t8 * 8)) = o8;
    }
}

// ---------- kernel 3: wave-specialized fp8 fused kernel, race-fixed ----------
// S-waves (0-3, role mi=w&1, ni=(w>>1)&1): full-K 32x32 S^T block (K=512, 32 fp8 mfma);
//   W8[t&1] = fp8(S256 * V). kn8 DOUBLE-buffered; each S-wave stages 16 rows, issues
//   kn8[t+1] at TOP of iter t and drains own glls (vmcnt(4)) BEFORE BAR(t) -> BAR
//   publishes the full 32-row tile block-wide (fixes R18's cross-wave race).
// C-waves (4-7, cw=w-4, d-slice cw*128): iter t does step3[t-1] (W8[(t-1)&1], kt8
//   private); post-loop does step3[63]. kt8[t] issued at iter t after step3 reads.
// Barriers: pro-BAR + 64 loop BARs = 65 on both paths.
// LDS 104 KiB: kn8[2 buf][2 mi][32 r][512] 64K | kt8[4 cw][128 dr][64] 32K | W8[2][64][64] 8K.
__global__ __launch_bounds__(512, 2) void fused_k(
    const unsigned char* __restrict__ xn8, const unsigned char* __restrict__ xnT8,
    const float* __restrict__ V, const float* __restrict__ bias,
    const float* __restrict__ x, float* __restrict__ out)
{
    __shared__ __align__(16) unsigned char smemB[106496];   // 104 KiB
    unsigned char* kn8B = smemB;             // [2 buf][2 mi][32 r][512B], 16B-unit phys = u ^ r
    unsigned char* kt8B = smemB + 65536;     // [4 cw][128 dr][64B], 16B-unit phys = u ^ ((dr>>1)&3)
    unsigned char* W8B  = smemB + 98304;     // [2 buf][64 q][64B], 4B-unit phys = u ^ (q&15)

    const int tid = threadIdx.x;
    const int w = tid >> 6, l = tid & 63;
    const int h = l >> 5, m32 = l & 31;

    // XCD-aware swizzle
    const int flat = blockIdx.y * 64 + blockIdx.x;
    const int work = (flat & 7) * 32 + (flat >> 3);
    const int b = work >> 6, qt = work & 63;
    const int q0 = qt * 64;

    const unsigned char* x8b = xn8  + (size_t)b * TT * DH;
    const unsigned char* xt8 = xnT8 + (size_t)b * DH * TT;

    if (w < 4) {
        // ================= S-group =================
        const int mi = w & 1, ni = (w >> 1) & 1;
        const int q = ni * 32 + m32;                       // lane's q row
        const float* vrow = V + (size_t)(q0 + q) * TT + mi * 32 + 4 * h;
        const int wkey = q & 15;                           // W8 write key
        const int srow = ni * 16 + ((l >> 5) ? 1 : 0);     // (used inside stage loops)

        // Q fp8 fragments over full K=512: 32 x i64v (64 VGPR)
        i64v qf8[32];
        #pragma unroll
        for (int ks = 0; ks < 32; ks++)
            qf8[ks] = *(const i64v*)(x8b + (size_t)(q0 + q) * DH + ks * 16 + h * 8);
        FENCE();
        // stage kn8[0] into buf0 (wave's 16 rows of its mi-slice)
        #pragma unroll
        for (int i = 0; i < 8; i++) {
            int r = ni * 16 + i * 2 + (l >> 5);
            int u16 = (l & 31) ^ r;
            const unsigned char* gp = x8b + (size_t)(mi * 32 + r) * DH + u16 * 16;
            __builtin_amdgcn_global_load_lds(
                (const __attribute__((address_space(1))) void*)gp,
                (__attribute__((address_space(3))) void*)&kn8B[mi * 16384 + (ni * 16 + i * 2) * 512], 16, 0, 0);
        }
        FENCE();
        floatx4 vf0 = *(const floatx4*)(vrow);
        floatx4 vf1 = *(const floatx4*)(vrow + 8);
        floatx4 vf2 = *(const floatx4*)(vrow + 16);
        floatx4 vf3 = *(const floatx4*)(vrow + 24);
        asm volatile("s_waitcnt vmcnt(4)" ::: "memory");   // qf8 + kn8[0] drained; V[0] in flight
        BAR();   // pro-BAR: kn8[0] published

        #pragma unroll 1
        for (int t = 0; t < 64; t++) {
            // ---- issue kn8[t+1] into the other buffer (read at t-1 -> WAR fenced by BAR) ----
            if (t < 63) {
                #pragma unroll
                for (int i = 0; i < 8; i++) {
                    int r = ni * 16 + i * 2 + (l >> 5);
                    int u16 = (l & 31) ^ r;
                    const unsigned char* gp = x8b + (size_t)((t+1)*64 + mi*32 + r) * DH + u16 * 16;
                    __builtin_amdgcn_global_load_lds(
                        (const __attribute__((address_space(1))) void*)gp,
                        (__attribute__((address_space(3))) void*)
                            &kn8B[((t+1) & 1) * 32768 + mi * 16384 + (ni * 16 + i * 2) * 512], 16, 0, 0);
                }
                FENCE();
            }
            // ---- step1 on buf[t&1]: 32 fp8 mfma, 4 chains ----
            const unsigned char* arow = kn8B + (t & 1) * 32768 + mi * 16384 + m32 * 512;
            floatx16 s0 = (floatx16)(0.f), s1 = (floatx16)(0.f);
            floatx16 s2 = (floatx16)(0.f), s3 = (floatx16)(0.f);
            __builtin_amdgcn_s_setprio(1);
            #pragma unroll
            for (int ks = 0; ks < 8; ks++) {
                i64v a0 = *(const i64v*)&arow[((ks      ) ^ m32) * 16 + h * 8];
                i64v a1 = *(const i64v*)&arow[((ks +  8) ^ m32) * 16 + h * 8];
                i64v a2 = *(const i64v*)&arow[((ks + 16) ^ m32) * 16 + h * 8];
                i64v a3 = *(const i64v*)&arow[((ks + 24) ^ m32) * 16 + h * 8];
                s0 = __builtin_amdgcn_mfma_f32_32x32x16_fp8_fp8(a0, qf8[ks     ], s0, 0, 0, 0);
                s1 = __builtin_amdgcn_mfma_f32_32x32x16_fp8_fp8(a1, qf8[ks +  8], s1, 0, 0, 0);
                s2 = __builtin_amdgcn_mfma_f32_32x32x16_fp8_fp8(a2, qf8[ks + 16], s2, 0, 0, 0);
                s3 = __builtin_amdgcn_mfma_f32_32x32x16_fp8_fp8(a3, qf8[ks + 24], s3, 0, 0, 0);
            }
            __builtin_amdgcn_s_setprio(0);
            floatx16 s = (s0 + s1) + (s2 + s3);
            // ---- W8[t&1] = fp8(S256 * V[t]) ----
            {
                unsigned char* Wb = W8B + (t & 1) * 4096 + q * 64;
                int p0 = __builtin_amdgcn_cvt_pk_fp8_f32(s[0]*vf0[0],  s[1]*vf0[1],  0, 0);
                p0     = __builtin_amdgcn_cvt_pk_fp8_f32(s[2]*vf0[2],  s[3]*vf0[3],  p0, 1);
                int p1 = __builtin_amdgcn_cvt_pk_fp8_f32(s[4]*vf1[0],  s[5]*vf1[1],  0, 0);
                p1     = __builtin_amdgcn_cvt_pk_fp8_f32(s[6]*vf1[2],  s[7]*vf1[3],  p1, 1);
                int p2 = __builtin_amdgcn_cvt_pk_fp8_f32(s[8]*vf2[0],  s[9]*vf2[1],  0, 0);
                p2     = __builtin_amdgcn_cvt_pk_fp8_f32(s[10]*vf2[2], s[11]*vf2[3], p2, 1);
                int p3 = __builtin_amdgcn_cvt_pk_fp8_f32(s[12]*vf3[0], s[13]*vf3[1], 0, 0);
                p3     = __builtin_amdgcn_cvt_pk_fp8_f32(s[14]*vf3[2], s[15]*vf3[3], p3, 1);
                *(uint32_t*)&Wb[((mi*8 + 0 + h) ^ wkey) * 4] = (uint32_t)p0;
                *(uint32_t*)&Wb[((mi*8 + 2 + h) ^ wkey) * 4] = (uint32_t)p1;
                *(uint32_t*)&Wb[((mi*8 + 4 + h) ^ wkey) * 4] = (uint32_t)p2;
                *(uint32_t*)&Wb[((mi*8 + 6 + h) ^ wkey) * 4] = (uint32_t)p3;
            }
            // ---- issue V[t+1] (after last vf use) ----
            if (t < 63) {
                FENCE();
                vf0 = *(const floatx4*)(vrow + (t+1)*64);
                vf1 = *(const floatx4*)(vrow + (t+1)*64 + 8);
                vf2 = *(const floatx4*)(vrow + (t+1)*64 + 16);
                vf3 = *(const floatx4*)(vrow + (t+1)*64 + 24);
                FENCE();
            }
            WAITLGKM();                                    // W8 writes + kn reads drained
            if (t < 63) { asm volatile("s_waitcnt vmcnt(4)" ::: "memory"); } // kn8[t+1] drained (V flying)
            BAR();   // publishes W8[t&1] and kn8[t+1]
        }
        // S-group: no epilogue
    } else {
        // ================= C-group =================
        const int cw = w - 4;
        unsigned char* ktS = kt8B + cw * 8192;
        const int db = cw * 128;
        const int keyW = m32 & 15;
        const int kk2 = (m32 >> 1) & 3;

        floatx16 acc[2][4];
        #pragma unroll
        for (int i = 0; i < 2; i++)
            #pragma unroll
            for (int j = 0; j < 4; j++)
                acc[i][j] = (floatx16)(0.f);

        // prologue: stage kt8[0]
        #pragma unroll
        for (int i = 0; i < 8; i++) {
            int dr = i * 16 + (l >> 2);
            int cs = (l & 3) ^ ((dr >> 1) & 3);
            const unsigned char* gp = xt8 + (size_t)(db + dr) * TT + cs * 16;
            __builtin_amdgcn_global_load_lds(
                (const __attribute__((address_space(1))) void*)gp,
                (__attribute__((address_space(3))) void*)&ktS[i * 1024], 16, 0, 0);
        }
        FENCE();
        BAR();   // pro-BAR

        #pragma unroll 1
        for (int t = 0; t < 64; t++) {
            if (t >= 1) {
                asm volatile("s_waitcnt vmcnt(0)" ::: "memory");   // kt8[t-1] landed
                const unsigned char* Wb = W8B + ((t - 1) & 1) * 4096;
                __builtin_amdgcn_s_setprio(1);
                #pragma unroll
                for (int ks = 0; ks < 4; ks++) {
                    union { uint32_t u[2]; i64v v; } wf0, wf1;
                    wf0.u[0] = *(const uint32_t*)&Wb[(m32     ) * 64 + ((ks*4 + 2*h    ) ^ keyW) * 4];
                    wf0.u[1] = *(const uint32_t*)&Wb[(m32     ) * 64 + ((ks*4 + 2*h + 1) ^ keyW) * 4];
                    wf1.u[0] = *(const uint32_t*)&Wb[(32 + m32) * 64 + ((ks*4 + 2*h    ) ^ keyW) * 4];
                    wf1.u[1] = *(const uint32_t*)&Wb[(32 + m32) * 64 + ((ks*4 + 2*h + 1) ^ keyW) * 4];
                    i64v kf[4];
                    #pragma unroll
                    for (int nd = 0; nd < 4; nd++) {
                        int dr = nd * 32 + m32;
                        kf[nd] = *(const i64v*)&ktS[dr * 64 + ((ks ^ kk2) * 16) + h * 8];
                    }
                    #pragma unroll
                    for (int nd = 0; nd < 4; nd++) {
                        acc[0][nd] = __builtin_amdgcn_mfma_f32_32x32x16_fp8_fp8(wf0.v, kf[nd], acc[0][nd], 0, 0, 0);
                        acc[1][nd] = __builtin_amdgcn_mfma_f32_32x32x16_fp8_fp8(wf1.v, kf[nd], acc[1][nd], 0, 0, 0);
                    }
                }
                __builtin_amdgcn_s_setprio(0);
                WAITLGKM();                                // ktS reads done -> safe to restage
                // issue kt8[t] (read at iter t+1 / post-loop)
                FENCE();
                #pragma unroll
                for (int i = 0; i < 8; i++) {
                    int dr = i * 16 + (l >> 2);
                    int cs = (l & 3) ^ ((dr >> 1) & 3);
                    const unsigned char* gp = xt8 + (size_t)(db + dr) * TT + t * 64 + cs * 16;
                    __builtin_amdgcn_global_load_lds(
                        (const __attribute__((address_space(1))) void*)gp,
                        (__attribute__((address_space(3))) void*)&ktS[i * 1024], 16, 0, 0);
                }
                FENCE();
            }
            BAR();
        }
        // post-loop: step3 for tile 63 (W8[1] published at last BAR; kt8[63] in flight)
        {
            asm volatile("s_waitcnt vmcnt(0)" ::: "memory");
            const unsigned char* Wb = W8B + (63 & 1) * 4096;
            #pragma unroll
            for (int ks = 0; ks < 4; ks++) {
                union { uint32_t u[2]; i64v v; } wf0, wf1;
                wf0.u[0] = *(const uint32_t*)&Wb[(m32     ) * 64 + ((ks*4 + 2*h    ) ^ keyW) * 4];
                wf0.u[1] = *(const uint32_t*)&Wb[(m32     ) * 64 + ((ks*4 + 2*h + 1) ^ keyW) * 4];
                wf1.u[0] = *(const uint32_t*)&Wb[(32 + m32) * 64 + ((ks*4 + 2*h    ) ^ keyW) * 4];
                wf1.u[1] = *(const uint32_t*)&Wb[(32 + m32) * 64 + ((ks*4 + 2*h + 1) ^ keyW) * 4];
                i64v kf[4];
                #pragma unroll
                for (int nd = 0; nd < 4; nd++) {
                    int dr = nd * 32 + m32;
                    kf[nd] = *(const i64v*)&ktS[dr * 64 + ((ks ^ kk2) * 16) + h * 8];
                }
                #pragma unroll
                for (int nd = 0; nd < 4; nd++) {
                    acc[0][nd] = __builtin_amdgcn_mfma_f32_32x32x16_fp8_fp8(wf0.v, kf[nd], acc[0][nd], 0, 0, 0);
                    acc[1][nd] = __builtin_amdgcn_mfma_f32_32x32x16_fp8_fp8(wf1.v, kf[nd], acc[1][nd], 0, 0, 0);
                }
            }
        }

        // ---- epilogue (C only): out = x_left * sigmoid(ctx/4096 + bias) ----
        const float* xb = x + (size_t)b * TT * 1024;
        float* ob = out + (size_t)b * TT * DH;
        const float isc = 1.0f / 4096.0f;
        #pragma unroll
        for (int ai = 0; ai < 2; ai++)
            #pragma unroll
            for (int nd = 0; nd < 4; nd++) {
                int d = db + nd * 32 + m32;
                float bv = bias[d];
                #pragma unroll
                for (int r = 0; r < 16; r++) {
                    int q = q0 + ai * 32 + (r & 3) + 8 * (r >> 2) + 4 * h;
                    float cv = acc[ai][nd][r] * isc + bv;
                    float gate = 1.0f / (1.0f + __expf(-cv));
                    ob[(size_t)q * DH + d] = xb[(size_t)q * 1024 + d] * gate;
                }
            }
    }
}

extern "C" void kernel_launch(void* const* d_in, const int* in_sizes, int n_in,
                              void* d_out, int out_size, void* d_ws, size_t ws_size,
                              hipStream_t stream) {
    const float* x    = (const float*)d_in[0];
    const float* V    = (const float*)d_in[1];
    const float* bias = (const float*)d_in[2];
    float* out = (float*)d_out;

    unsigned short* xn   = (unsigned short*)d_ws;                   // [4][4096][512] fp16, 16MB
    unsigned char*  xn8  = (unsigned char*)(xn + (size_t)4 * TT * DH);  // fp8, 8MB
    unsigned char*  xnT8 = xn8 + (size_t)4 * TT * DH;               // [4][512][4096] fp8, 8MB

    norm_k<<<dim3(4 * TT / 4), 256, 0, stream>>>(x, xn, xn8);
    transpose_k<<<dim3(TT / 64, DH / 64, 4), 256, 0, stream>>>(xn, xnT8);
    fused_k<<<dim3(TT / 64, 4), 512, 0, stream>>>(xn8, xnT8, V, bias, x, out);
}